// Round 7
// baseline (323.311 us; speedup 1.0000x reference)
//
#include <hip/hip_runtime.h>
#include <stdint.h>

#define B_ 4
#define T_ 4096
#define D_ 1024
#define H_ 16
#define NPAD 2304            // 1024 k + 1024 v + 16 beta + 16 g + 224 zero-pad (multiple of 256)
#define ROWS (B_*T_)         // 16384

typedef __bf16 bf16x8 __attribute__((ext_vector_type(8)));
typedef float  f32x4  __attribute__((ext_vector_type(4)));
typedef unsigned short u16;
typedef u16 u16x8 __attribute__((ext_vector_type(8)));
typedef u16 u16x4 __attribute__((ext_vector_type(4)));

__device__ __forceinline__ float bf2f(u16 u){
  union { unsigned int i; float f; } x; x.i = ((unsigned int)u) << 16; return x.f;
}
__device__ __forceinline__ u16 f2bf(float f){
  union { float f; unsigned int i; } x; x.f = f;
  unsigned int r = x.i + 0x7fffu + ((x.i >> 16) & 1u);
  return (u16)(r >> 16);
}
__device__ __forceinline__ bf16x8 as_bf(u16x8 v){ union{u16x8 u; bf16x8 b;} x; x.u = v; return x.b; }

__device__ __forceinline__ void gload_lds16(const u16* g, u16* l){
  __builtin_amdgcn_global_load_lds(
      (const __attribute__((address_space(1))) unsigned int*)g,
      (__attribute__((address_space(3))) unsigned int*)l, 16, 0, 0);
}

// ---------------- weight prep ----------------
__global__ __launch_bounds__(256) void prep_w(
    const float* __restrict__ Wk, const float* __restrict__ Wv,
    const float* __restrict__ Wb, const float* __restrict__ Wg,
    const float* __restrict__ Wo, u16* __restrict__ Wcomb, u16* __restrict__ Wob)
{
  long i = (long)blockIdx.x * 256 + threadIdx.x;
  const long tot1 = (long)NPAD * D_;
  if (i < tot1) {
    long n = i >> 10, d = i & 1023;
    float v;
    if      (n < 1024) v = Wk[n * 1024 + d];
    else if (n < 2048) v = Wv[(n - 1024) * 1024 + d];
    else if (n < 2064) v = Wb[(n - 2048) * 1024 + d];
    else if (n < 2080) v = Wg[(n - 2064) * 1024 + d];
    else               v = 0.f;
    Wcomb[i] = f2bf(v);
  } else {
    long j = i - tot1;
    Wob[j] = f2bf(Wo[j]);
  }
}

// ---------------- RMSNorm ----------------
__global__ __launch_bounds__(256) void rmsnorm_k(
    const float* __restrict__ x, const float* __restrict__ w, u16* __restrict__ xn)
{
  long row = blockIdx.x;
  int tid = threadIdx.x;
  int l = tid & 63, wv = tid >> 6;
  f32x4 v = ((const f32x4*)(x + row * D_))[tid];
  float ss = v[0]*v[0] + v[1]*v[1] + v[2]*v[2] + v[3]*v[3];
  #pragma unroll
  for (int m = 1; m < 64; m <<= 1) ss += __shfl_xor(ss, m, 64);
  __shared__ float red[4];
  if (l == 0) red[wv] = ss;
  __syncthreads();
  float tot = red[0] + red[1] + red[2] + red[3];
  float inv = rsqrtf(tot * (1.f / (float)D_) + 1e-6f);
  f32x4 wv4 = ((const f32x4*)w)[tid];
  u16x4 o;
  o[0] = f2bf(v[0] * inv * wv4[0]);
  o[1] = f2bf(v[1] * inv * wv4[1]);
  o[2] = f2bf(v[2] * inv * wv4[2]);
  o[3] = f2bf(v[3] * inv * wv4[3]);
  ((u16x4*)(xn + row * D_))[tid] = o;
}

// ---------------- 256x256 deep-pipelined bf16 NT GEMM ----------------
// BK=32, 8 waves (2x4), 4 LDS buffers (128KB dynamic), prefetch distance 3,
// ONE barrier per tile, vmcnt(8) counted (never drained), uniform-bank swizzle,
// stage issued right after barrier, batched 12 ds_read -> 32 MFMA (setprio).
extern __shared__ f32x4 lds_dyn[];

template<int RESID, int OUTF32>
__global__ __launch_bounds__(512, 2) void gemm256(
    const u16* __restrict__ A, const u16* __restrict__ Bm,
    u16* __restrict__ Cb, float* __restrict__ Cf, const float* __restrict__ resid,
    int M, int N, int Kd)
{
  const int tid = threadIdx.x;
  const int w = tid >> 6, l = tid & 63;
  const int lm = l & 15, lq = l >> 4;
  const int wm = w >> 2, wn = w & 3;

  unsigned gx = gridDim.x;
  unsigned bid = blockIdx.y * gx + blockIdx.x;
  unsigned nwg = gx * gridDim.y;
  unsigned cpx = nwg >> 3;
  unsigned swz = (bid & 7) * cpx + (bid >> 3);
  const long bm0 = (long)(swz / gx) * 256;
  const long bn0 = (long)(swz % gx) * 256;

  char* lds = (char*)lds_dyn;

  int rowS[2];
  #pragma unroll
  for (int r = 0; r < 2; ++r) rowS[r] = r*128 + w*16 + (l >> 2);
  const int colS = ((l & 3) ^ ((l >> 3) & 3)) * 8;

  auto STAGE = [&](int t, int q){
    char* base = lds + q*32768;
    long k0 = (long)t * 32;
    #pragma unroll
    for (int r = 0; r < 2; ++r)
      gload_lds16(A + (bm0 + rowS[r])*(long)Kd + k0 + colS,
                  (u16*)(base + (r*512 + w*64)*16));
    #pragma unroll
    for (int r = 0; r < 2; ++r)
      gload_lds16(Bm + (bn0 + rowS[r])*(long)Kd + k0 + colS,
                  (u16*)(base + 16384 + (r*512 + w*64)*16));
  };

  const unsigned soff = (unsigned)(lq ^ ((lm >> 1) & 3)) << 4;

  f32x4 acc[8][4];
  #pragma unroll
  for (int i = 0; i < 8; ++i)
    #pragma unroll
    for (int j = 0; j < 4; ++j) acc[i][j] = f32x4{0.f,0.f,0.f,0.f};

  const int NT = Kd >> 5;     // 32
  STAGE(0, 0);
  STAGE(1, 1);
  STAGE(2, 2);

  for (int t = 0; t < NT; ++t) {
    int q  = t & 3;
    int qn = (t + 3) & 3;
    int tn = (t + 3 < NT) ? (t + 3) : (NT - 1);

    asm volatile("s_waitcnt vmcnt(8)" ::: "memory");
    __builtin_amdgcn_s_barrier();
    asm volatile("" ::: "memory");

    STAGE(tn, qn);              // issue next-next-next tile ASAP (max latency cover)

    const char* Ab = lds + q*32768;
    const char* Bb = Ab + 16384;

    bf16x8 bfr[4], afr[8];
    #pragma unroll
    for (int nf = 0; nf < 4; ++nf) {
      int rr = wn*64 + nf*16 + lm;
      bfr[nf] = *(const bf16x8*)(Bb + rr*64 + soff);
    }
    #pragma unroll
    for (int mf = 0; mf < 8; ++mf) {
      int rr = wm*128 + mf*16 + lm;
      afr[mf] = *(const bf16x8*)(Ab + rr*64 + soff);
    }

    __builtin_amdgcn_s_setprio(1);
    #pragma unroll
    for (int mf = 0; mf < 8; ++mf)
      #pragma unroll
      for (int nf = 0; nf < 4; ++nf)
        acc[mf][nf] = __builtin_amdgcn_mfma_f32_16x16x32_bf16(afr[mf], bfr[nf], acc[mf][nf], 0, 0, 0);
    __builtin_amdgcn_s_setprio(0);
  }

  #pragma unroll
  for (int mf = 0; mf < 8; ++mf) {
    #pragma unroll
    for (int r = 0; r < 4; ++r) {
      long m = bm0 + wm*128 + mf*16 + lq*4 + r;
      #pragma unroll
      for (int nf = 0; nf < 4; ++nf) {
        long n = bn0 + wn*64 + nf*16 + lm;
        float val = acc[mf][nf][r];
        if (RESID) val += resid[m * N + n];
        if (OUTF32) Cf[m * N + n] = val;
        else        Cb[m * N + n] = f2bf(val);
      }
    }
  }
}

// ---------------- fallback bf16 NT GEMM (validated, 128^2) ----------------
template<int RESID, int OUTF32>
__global__ __launch_bounds__(256) void gemm_nt(
    const u16* __restrict__ A, const u16* __restrict__ Bm,
    u16* __restrict__ Cb, float* __restrict__ Cf, const float* __restrict__ resid,
    int M, int N, int Kd)
{
  __shared__ __align__(16) u16 Als[128 * 32];
  __shared__ __align__(16) u16 Bls[128 * 32];
  const int tid = threadIdx.x;
  const int w = tid >> 6, l = tid & 63;
  const int wr = w >> 1, wc = w & 1;
  const int lm = l & 15, lq = l >> 4;

  unsigned bid = blockIdx.y * gridDim.x + blockIdx.x;
  unsigned nwg = gridDim.x * gridDim.y;
  unsigned cpx = nwg >> 3;
  unsigned swz = (bid & 7) * cpx + (bid >> 3);
  const long bm0 = (long)(swz / gridDim.x) * 128;
  const long bn0 = (long)(swz % gridDim.x) * 128;

  f32x4 zero4 = {0.f, 0.f, 0.f, 0.f};
  f32x4 acc[4][4];
  #pragma unroll
  for (int i = 0; i < 4; i++)
    #pragma unroll
    for (int j = 0; j < 4; j++) acc[i][j] = zero4;

  for (int kk = 0; kk < Kd; kk += 32) {
    __syncthreads();
    #pragma unroll
    for (int it = 0; it < 2; it++) {
      int c = tid + it * 256;
      int r = c >> 2, kb = c & 3;
      const u16* ga = A  + (bm0 + r) * Kd + kk + kb * 8;
      const u16* gb = Bm + (bn0 + r) * Kd + kk + kb * 8;
      gload_lds16(ga, Als + (it * 256 + w * 64) * 8);
      gload_lds16(gb, Bls + (it * 256 + w * 64) * 8);
    }
    __syncthreads();
    bf16x8 af[4], bfr[4];
    #pragma unroll
    for (int f = 0; f < 4; f++)
      af[f] = *(const bf16x8*)(Als + (wr * 64 + f * 16 + lm) * 32 + lq * 8);
    #pragma unroll
    for (int f = 0; f < 4; f++)
      bfr[f] = *(const bf16x8*)(Bls + (wc * 64 + f * 16 + lm) * 32 + lq * 8);
    #pragma unroll
    for (int i = 0; i < 4; i++)
      #pragma unroll
      for (int j = 0; j < 4; j++)
        acc[i][j] = __builtin_amdgcn_mfma_f32_16x16x32_bf16(af[i], bfr[j], acc[i][j], 0, 0, 0);
  }

  #pragma unroll
  for (int i = 0; i < 4; i++) {
    #pragma unroll
    for (int r = 0; r < 4; r++) {
      long m = bm0 + wr * 64 + i * 16 + lq * 4 + r;
      #pragma unroll
      for (int j = 0; j < 4; j++) {
        long n = bn0 + wc * 64 + j * 16 + lm;
        float val = acc[i][j][r];
        if (RESID) val += resid[m * N + n];
        if (OUTF32) Cf[m * N + n] = val;
        else        Cb[m * N + n] = f2bf(val);
      }
    }
  }
}

// ---------------- sigmoid for beta/g ----------------
__global__ __launch_bounds__(256) void sigmoid_bg(
    const u16* __restrict__ kv, const float* __restrict__ bb, const float* __restrict__ bg,
    float* __restrict__ bArr, float* __restrict__ gArr)
{
  int idx = blockIdx.x * 256 + threadIdx.x;   // ROWS*32 total
  int row = idx >> 5, c = idx & 31;
  int h = c & 15;
  float val = bf2f(kv[(long)row * NPAD + 2048 + c]) + ((c < 16) ? bb[h] : bg[h]);
  float s = 1.f / (1.f + expf(-val));
  long b = row >> 12, t = row & 4095;
  float* dst = (c < 16) ? bArr : gArr;
  dst[(b * H_ + h) * (long)T_ + t] = s;
}

// 64x64x64 NT matmul from LDS bf16 tiles (stride 72)
__device__ __forceinline__ void mm64(const u16* Ab, const u16* Bb,
                                     int lm, int lq, int wr, int wc, f32x4 acc[2][2])
{
  #pragma unroll
  for (int ks = 0; ks < 2; ++ks) {
    bf16x8 af[2], bfr[2];
    #pragma unroll
    for (int mi = 0; mi < 2; ++mi)
      af[mi] = *(const bf16x8*)(Ab + (wr*32 + mi*16 + lm)*72 + ks*32 + lq*8);
    #pragma unroll
    for (int ni = 0; ni < 2; ++ni)
      bfr[ni] = *(const bf16x8*)(Bb + (wc*32 + ni*16 + lm)*72 + ks*32 + lq*8);
    #pragma unroll
    for (int mi = 0; mi < 2; ++mi)
      #pragma unroll
      for (int ni = 0; ni < 2; ++ni)
        acc[mi][ni] = __builtin_amdgcn_mfma_f32_16x16x32_bf16(af[mi], bfr[ni], acc[mi][ni], 0, 0, 0);
  }
}

// ---------------- phase 1: per-chunk WY factors ----------------
__global__ __launch_bounds__(256) void chunk1(
    u16* __restrict__ kv, const float* __restrict__ bArr, const float* __restrict__ gArr,
    u16* __restrict__ p1buf, u16* __restrict__ r1buf)
{
  __shared__ __align__(16) u16 Kb[64*72];      // raw K chunk [s][k]
  __shared__ __align__(16) u16 Utb[128*72];    // V staged -> U^T
  __shared__ __align__(16) u16 LpI[64*72];
  __shared__ __align__(16) u16 Abf[64*72];     // off-diag A (diag zero) -> later Ktb
  __shared__ __align__(16) u16 Adb[4*16*24];   // bf16 diag-block A, stride 24
  __shared__ float nrm2LS[64];
  __shared__ float aLS[64], ainvLS[64], bLS[64], bapLS[64];
  __shared__ float aCsh;

  const int tid = threadIdx.x;
  const int w = tid >> 6, l = tid & 63;
  const int lm = l & 15, lq = l >> 4;
  const int wr = w >> 1, wc = w & 1;
  const int bh = blockIdx.x & 63, ch = blockIdx.x >> 6;
  const int b = bh >> 4, h = bh & 15;

  const u16* kbase = kv + ((long)b*T_ + ch*64)*NPAD + h*64;
  const u16* vbase = kbase + 1024;

  #pragma unroll
  for (int it = 0; it < 2; ++it) {
    int c = tid + it*256;
    int r = c >> 3, seg = (c & 7)*8;
    *(u16x8*)(Kb  + r*72 + seg) = *(const u16x8*)(kbase + (long)r*NPAD + seg);
    *(u16x8*)(Utb + r*72 + seg) = *(const u16x8*)(vbase + (long)r*NPAD + seg);
  }
  #pragma unroll
  for (int z = 0; z < 8; ++z) {
    int idx = tid + z*256;
    int rr = idx >> 5, wd = idx & 31;
    ((unsigned int*)(Utb + (64 + rr)*72))[wd] = 0u;
  }
  if (tid < 64) {
    float gv = gArr[(long)bh*T_ + ch*64 + tid];
    float bv = bArr[(long)bh*T_ + ch*64 + tid];
    float av = gv;
    #pragma unroll
    for (int off = 1; off < 64; off <<= 1) {
      float o = __shfl_up(av, off, 64);
      if (tid >= off) av *= o;
    }
    float ap = __shfl_up(av, 1, 64);
    if (tid == 0) ap = 1.f;
    float aC = __shfl(av, 63, 64);
    aLS[tid] = av; ainvLS[tid] = 1.f/av; bLS[tid] = bv; bapLS[tid] = bv*ap;
    if (tid == 0) aCsh = aC;
  }
  __syncthreads();   // bar1

  f32x4 gf[2][2];
  #pragma unroll
  for (int mi = 0; mi < 2; ++mi)
    #pragma unroll
    for (int ni = 0; ni < 2; ++ni) gf[mi][ni] = f32x4{0.f,0.f,0.f,0.f};
  mm64(Kb, Kb, lm, lq, wr, wc, gf);

  #pragma unroll
  for (int mi = 0; mi < 2; ++mi)
    #pragma unroll
    for (int ni = 0; ni < 2; ++ni)
      #pragma unroll
      for (int r = 0; r < 4; ++r) {
        int row = wr*32 + mi*16 + lq*4 + r, col = wc*32 + ni*16 + lm;
        if (row == col) nrm2LS[row] = gf[mi][ni][r];
      }
  __syncthreads();   // bar1.5
  if (tid < 64) {
    float nv = 1.f / fmaxf(sqrtf(nrm2LS[tid]), 1e-12f);
    aLS[tid] *= nv; ainvLS[tid] *= nv; bapLS[tid] *= nv;
  }
  __syncthreads();   // bar1.75

  float wv_[4][2][4];
  #pragma unroll
  for (int bi = 0; bi < 4; ++bi)
    #pragma unroll
    for (int ni = 0; ni < 2; ++ni) {
      int col = w*32 + ni*16 + lm;
      #pragma unroll
      for (int r = 0; r < 4; ++r) {
        int row = bi*16 + lq*4 + r;
        float sv = (col < 64) ? bf2f(Utb[row*72 + col]) : bf2f(Kb[row*72 + (col - 64)]);
        float coef = (col < 64) ? bLS[row] : bapLS[row];
        wv_[bi][ni][r] = coef * sv;
      }
    }

  #pragma unroll
  for (int mi = 0; mi < 2; ++mi)
    #pragma unroll
    for (int ni = 0; ni < 2; ++ni)
      #pragma unroll
      for (int r = 0; r < 4; ++r) {
        int row = wr*32 + mi*16 + lq*4 + r, col = wc*32 + ni*16 + lm;
        float gvl = gf[mi][ni][r];
        int rb = row >> 4, cb = col >> 4;
        Abf[row*72 + col] = f2bf((rb > cb) ? bapLS[row]*ainvLS[col]*gvl : 0.f);
        if (rb == cb)
          Adb[rb*384 + (row & 15)*24 + (col & 15)] =
              f2bf(((col & 15) < (row & 15)) ? bapLS[row]*ainvLS[col]*gvl : 0.f);
        LpI[row*72 + col] = f2bf((col < row) ? aLS[row]*ainvLS[col]*gvl
                                             : ((col == row) ? 1.f : 0.f));
      }
  __syncthreads();   // bar2

  #pragma unroll
  for (int bi = 0; bi < 4; ++bi) {
    if (bi > 0) {
      f32x4 corr[2] = { f32x4{0.f,0.f,0.f,0.f}, f32x4{0.f,0.f,0.f,0.f} };
      const int nks = (bi*16 + 31) >> 5;
      #pragma unroll
      for (int ks = 0; ks < 2; ++ks) {
        if (ks < nks) {
          bf16x8 afr = *(const bf16x8*)(Abf + (bi*16 + lm)*72 + ks*32 + lq*8);
          #pragma unroll
          for (int ni = 0; ni < 2; ++ni) {
            bf16x8 bfr = *(const bf16x8*)(Utb + (w*32 + ni*16 + lm)*72 + ks*32 + lq*8);
            corr[ni] = __builtin_amdgcn_mfma_f32_16x16x32_bf16(afr, bfr, corr[ni], 0, 0, 0);
          }
        }
      }
      #pragma unroll
      for (int ni = 0; ni < 2; ++ni)
        #pragma unroll
        for (int r = 0; r < 4; ++r) wv_[bi][ni][r] -= corr[ni][r];
    }
    u16x8 ad0[4], ad1[4];
    #pragma unroll
    for (int r = 0; r < 4; ++r) {
      ad0[r] = *(const u16x8*)(Adb + bi*384 + (lq*4 + r)*24);
      ad1[r] = *(const u16x8*)(Adb + bi*384 + (lq*4 + r)*24 + 8);
    }
    #pragma unroll
    for (int i = 0; i < 16; ++i) {
      int src = ((i >> 2) << 4) | lm;
      float u0 = __shfl(wv_[bi][0][i & 3], src, 64);
      float u1 = __shfl(wv_[bi][1][i & 3], src, 64);
      #pragma unroll
      for (int r = 0; r < 4; ++r) {
        float ad = bf2f((i < 8) ? ad0[r][i] : ad1[r][i - 8]);
        wv_[bi][0][r] = fmaf(-ad, u0, wv_[bi][0][r]);
        wv_[bi][1][r] = fmaf(-ad, u1, wv_[bi][1][r]);
      }
    }
    #pragma unroll
    for (int ni = 0; ni < 2; ++ni) {
      int col = w*32 + ni*16 + lm;
      #pragma unroll
      for (int r = 0; r < 4; ++r)
        Utb[col*72 + bi*16 + lq*4 + r] = f2bf(wv_[bi][ni][r]);
    }
  }
  __syncthreads();   // bar3

  const long pr_base = (((long)bh*64 + ch)*64);
  u16* qdst = kv + ((long)b*T_ + ch*64)*NPAD + h*64;
  u16* mdst = qdst + 1024;
  f32x4 acc[2][2];

  #pragma unroll
  for (int mi = 0; mi < 2; ++mi)
    #pragma unroll
    for (int ni = 0; ni < 2; ++ni) acc[mi][ni] = f32x4{0.f,0.f,0.f,0.f};
  mm64(Utb, LpI, lm, lq, wr, wc, acc);
  #pragma unroll
  for (int mi = 0; mi < 2; ++mi)
    #pragma unroll
    for (int ni = 0; ni < 2; ++ni)
      #pragma unroll
      for (int r = 0; r < 4; ++r) {
        int row = wr*32 + mi*16 + lq*4 + r, col = wc*32 + ni*16 + lm;
        p1buf[(pr_base + row)*64 + col] = f2bf(acc[mi][ni][r]);
      }

  #pragma unroll
  for (int mi = 0; mi < 2; ++mi)
    #pragma unroll
    for (int ni = 0; ni < 2; ++ni) acc[mi][ni] = f32x4{0.f,0.f,0.f,0.f};
  mm64(LpI, Utb + 64*72, lm, lq, wr, wc, acc);
  #pragma unroll
  for (int mi = 0; mi < 2; ++mi)
    #pragma unroll
    for (int ni = 0; ni < 2; ++ni)
      #pragma unroll
      for (int r = 0; r < 4; ++r) {
        int row = wr*32 + mi*16 + lq*4 + r, col = wc*32 + ni*16 + lm;
        float val = aLS[row]*bf2f(Kb[row*72 + col]) - acc[mi][ni][r];
        qdst[(long)row*NPAD + col] = f2bf(val);
      }

  {
    int s = tid & 63, kk0 = (tid >> 6) * 16;
    float coef = aCsh * ainvLS[s];
    #pragma unroll
    for (int j = 0; j < 16; ++j)
      Abf[(kk0 + j)*72 + s] = f2bf(coef * bf2f(Kb[s*72 + kk0 + j]));
  }
  __syncthreads();   // bar4

  #pragma unroll
  for (int mi = 0; mi < 2; ++mi)
    #pragma unroll
    for (int ni = 0; ni < 2; ++ni) acc[mi][ni] = f32x4{0.f,0.f,0.f,0.f};
  mm64(Utb, Abf, lm, lq, wr, wc, acc);
  #pragma unroll
  for (int mi = 0; mi < 2; ++mi)
    #pragma unroll
    for (int ni = 0; ni < 2; ++ni)
      #pragma unroll
      for (int r = 0; r < 4; ++r) {
        int row = wr*32 + mi*16 + lq*4 + r, col = wc*32 + ni*16 + lm;
        r1buf[(pr_base + row)*64 + col] = f2bf(acc[mi][ni][r]);
      }

  #pragma unroll
  for (int mi = 0; mi < 2; ++mi)
    #pragma unroll
    for (int ni = 0; ni < 2; ++ni) acc[mi][ni] = f32x4{0.f,0.f,0.f,0.f};
  mm64(Abf, Utb + 64*72, lm, lq, wr, wc, acc);
  #pragma unroll
  for (int mi = 0; mi < 2; ++mi)
    #pragma unroll
    for (int ni = 0; ni < 2; ++ni)
      #pragma unroll
      for (int r = 0; r < 4; ++r) {
        int row = wr*32 + mi*16 + lq*4 + r, col = wc*32 + ni*16 + lm;
        float val = ((row == col) ? aCsh : 0.f) - acc[mi][ni][r];
        mdst[(long)row*NPAD + col] = f2bf(val);
      }
}

// ---------------- phase 2: sequential chunk recurrence ----------------
struct PF { u16x8 qf0, qf1, mf0, mf1; u16 p1[4]; u16 r1[4]; };

__global__ __launch_bounds__(256) void chunk2(
    const u16* __restrict__ kv, const u16* __restrict__ p1buf, const u16* __restrict__ r1buf,
    u16* __restrict__ outb)
{
  __shared__ __align__(16) u16 Zb[16*72];
  __shared__ __align__(16) u16 ot[64*24];
  const int tid = threadIdx.x;
  const int wcv = tid >> 6, l = tid & 63;
  const int lm = l & 15, lq = l >> 4;
  const int bh = blockIdx.x & 63, vg = blockIdx.x >> 6;
  const int b = bh >> 4, h = bh & 15;

  for (int idx = tid; idx < 16*72/2; idx += 256) ((unsigned int*)Zb)[idx] = 0u;

  const u16* pbase = p1buf + (long)bh*64*4096;
  const u16* rbase = r1buf + (long)bh*64*4096;

  auto LOADPF = [&](int ch, PF& p){
    long rq = ((long)b*T_ + ch*64 + wcv*16 + lm)*NPAD + h*64 + lq*8;
    p.qf0 = *(const u16x8*)(kv + rq);
    p.qf1 = *(const u16x8*)(kv + rq + 32);
    p.mf0 = *(const u16x8*)(kv + rq + 1024);
    p.mf1 = *(const u16x8*)(kv + rq + 1024 + 32);
    #pragma unroll
    for (int r = 0; r < 4; ++r) {
      long pv = (long)ch*4096 + (vg*16 + lq*4 + r)*64 + wcv*16 + lm;
      p.p1[r] = pbase[pv];
      p.r1[r] = rbase[pv];
    }
  };

  PF A, Bp;
  LOADPF(0, A);
  __syncthreads();

  auto STEP = [&](int ch, PF& use, PF& pre){
    bf16x8 za0 = *(const bf16x8*)(Zb + lm*72 + lq*8);
    bf16x8 za1 = *(const bf16x8*)(Zb + lm*72 + 32 + lq*8);
    if (ch < 63) LOADPF(ch + 1, pre);
    f32x4 accO = { bf2f(use.p1[0]), bf2f(use.p1[1]), bf2f(use.p1[2]), bf2f(use.p1[3]) };
    accO = __builtin_amdgcn_mfma_f32_16x16x32_bf16(za0, as_bf(use.qf0), accO, 0, 0, 0);
    accO = __builtin_amdgcn_mfma_f32_16x16x32_bf16(za1, as_bf(use.qf1), accO, 0, 0, 0);
    f32x4 accS = { bf2f(use.r1[0]), bf2f(use.r1[1]), bf2f(use.r1[2]), bf2f(use.r1[3]) };
    accS = __builtin_amdgcn_mfma_f32_16x16x32_bf16(za0, as_bf(use.mf0), accS, 0, 0, 0);
    accS = __builtin_amdgcn_mfma_f32_16x16x32_bf16(za1, as_bf(use.mf1), accS, 0, 0, 0);
    #pragma unroll
    for (int r = 0; r < 4; ++r) ot[(wcv*16 + lm)*24 + lq*4 + r] = f2bf(accO[r]);
    __syncthreads();
    #pragma unroll
    for (int r = 0; r < 4; ++r) Zb[(lq*4 + r)*72 + wcv*16 + lm] = f2bf(accS[r]);
    {
      int i2 = tid >> 2, q4 = tid & 3;
      u16x4 ov = *(const u16x4*)(ot + i2*24 + q4*4);
      *(u16x4*)(outb + ((long)b*T_ + ch*64 + i2)*D_ + h*64 + vg*16 + q4*4) = ov;
    }
    __syncthreads();
  };

  for (int c2 = 0; c2 < 32; ++c2) {
    STEP(2*c2,     A, Bp);
    STEP(2*c2 + 1, Bp, A);
  }
}

extern "C" void kernel_launch(void* const* d_in, const int* in_sizes, int n_in,
                              void* d_out, int out_size, void* d_ws, size_t ws_size,
                              hipStream_t stream) {
  const float* x     = (const float*)d_in[0];
  const float* normw = (const float*)d_in[1];
  const float* Wk    = (const float*)d_in[2];
  const float* Wv    = (const float*)d_in[3];
  const float* Wo    = (const float*)d_in[4];
  const float* Wb    = (const float*)d_in[5];
  const float* bb    = (const float*)d_in[6];
  const float* Wg    = (const float*)d_in[7];
  const float* bg    = (const float*)d_in[8];
  float* y = (float*)d_out;

  char* ws = (char*)d_ws;
  u16* xn    = (u16*)ws;   ws += (long)ROWS * D_ * 2;      // 33.5 MB (reused as P1^T)
  u16* Wcomb = (u16*)ws;   ws += (long)NPAD * D_ * 2;      // 4.7 MB
  u16* Wob   = (u16*)ws;   ws += (long)D_ * D_ * 2;        // 2 MB
  u16* kvb   = (u16*)ws;   ws += (long)ROWS * NPAD * 2;    // 75.5 MB (k,v -> Q,M in place)
  float* bA  = (float*)ws; ws += (long)B_ * H_ * T_ * 4;
  float* gA  = (float*)ws; ws += (long)B_ * H_ * T_ * 4;
  u16* outb  = (u16*)ws;   ws += (long)ROWS * D_ * 2;
  u16* r1b   = (u16*)ws;   ws += (long)64 * 64 * 4096 * 2; // R1^T

  const int LDSB = 4 * 32768;   // 128 KB, 4-buffer distance-3 pipeline
  bool big = true;
  if (hipFuncSetAttribute(reinterpret_cast<const void*>(gemm256<0,0>),
        hipFuncAttributeMaxDynamicSharedMemorySize, LDSB) != hipSuccess) big = false;
  if (hipFuncSetAttribute(reinterpret_cast<const void*>(gemm256<1,1>),
        hipFuncAttributeMaxDynamicSharedMemorySize, LDSB) != hipSuccess) big = false;

  const long prep_total = (long)NPAD * D_ + (long)D_ * D_;
  prep_w<<<dim3((unsigned)(prep_total / 256)), dim3(256), 0, stream>>>(
      Wk, Wv, Wb, Wg, Wo, Wcomb, Wob);
  rmsnorm_k<<<dim3(ROWS), dim3(256), 0, stream>>>(x, normw, xn);
  if (big)
    gemm256<0, 0><<<dim3(NPAD / 256, ROWS / 256), dim3(512), LDSB, stream>>>(
        xn, Wcomb, kvb, (float*)nullptr, (const float*)nullptr, ROWS, NPAD, D_);
  else
    gemm_nt<0, 0><<<dim3(NPAD / 128, ROWS / 128), dim3(256), 0, stream>>>(
        xn, Wcomb, kvb, (float*)nullptr, (const float*)nullptr, ROWS, NPAD, D_);
  sigmoid_bg<<<dim3(ROWS * 32 / 256), dim3(256), 0, stream>>>(kvb, bb, bg, bA, gA);
  chunk1<<<dim3(4096), dim3(256), 0, stream>>>(kvb, bA, gA, xn, r1b);
  chunk2<<<dim3(256), dim3(256), 0, stream>>>(kvb, xn, r1b, outb);
  if (big)
    gemm256<1, 1><<<dim3(D_ / 256, ROWS / 256), dim3(512), LDSB, stream>>>(
        outb, Wob, (u16*)nullptr, y, x, ROWS, D_, D_);
  else
    gemm_nt<1, 1><<<dim3(D_ / 128, ROWS / 128), dim3(256), 0, stream>>>(
        outb, Wob, (u16*)nullptr, y, x, ROWS, D_, D_);
}

// Round 8
// 310.906 us; speedup vs baseline: 1.0399x; 1.0399x over previous
//
#include <hip/hip_runtime.h>
#include <stdint.h>

#define B_ 4
#define T_ 4096
#define D_ 1024
#define H_ 16
#define NPAD 2304            // 1024 k + 1024 v + 16 beta + 16 g + 224 zero-pad (multiple of 256)
#define ROWS (B_*T_)         // 16384

typedef __bf16 bf16x8 __attribute__((ext_vector_type(8)));
typedef float  f32x4  __attribute__((ext_vector_type(4)));
typedef unsigned short u16;
typedef u16 u16x8 __attribute__((ext_vector_type(8)));
typedef u16 u16x4 __attribute__((ext_vector_type(4)));

__device__ __forceinline__ float bf2f(u16 u){
  union { unsigned int i; float f; } x; x.i = ((unsigned int)u) << 16; return x.f;
}
__device__ __forceinline__ u16 f2bf(float f){
  union { float f; unsigned int i; } x; x.f = f;
  unsigned int r = x.i + 0x7fffu + ((x.i >> 16) & 1u);
  return (u16)(r >> 16);
}
__device__ __forceinline__ bf16x8 as_bf(u16x8 v){ union{u16x8 u; bf16x8 b;} x; x.u = v; return x.b; }

__device__ __forceinline__ void gload_lds16(const u16* g, u16* l){
  __builtin_amdgcn_global_load_lds(
      (const __attribute__((address_space(1))) unsigned int*)g,
      (__attribute__((address_space(3))) unsigned int*)l, 16, 0, 0);
}

// ---------------- weight prep ----------------
__global__ __launch_bounds__(256) void prep_w(
    const float* __restrict__ Wk, const float* __restrict__ Wv,
    const float* __restrict__ Wb, const float* __restrict__ Wg,
    const float* __restrict__ Wo, u16* __restrict__ Wcomb, u16* __restrict__ Wob)
{
  long i = (long)blockIdx.x * 256 + threadIdx.x;
  const long tot1 = (long)NPAD * D_;
  if (i < tot1) {
    long n = i >> 10, d = i & 1023;
    float v;
    if      (n < 1024) v = Wk[n * 1024 + d];
    else if (n < 2048) v = Wv[(n - 1024) * 1024 + d];
    else if (n < 2064) v = Wb[(n - 2048) * 1024 + d];
    else if (n < 2080) v = Wg[(n - 2064) * 1024 + d];
    else               v = 0.f;
    Wcomb[i] = f2bf(v);
  } else {
    long j = i - tot1;
    Wob[j] = f2bf(Wo[j]);
  }
}

// ---------------- RMSNorm ----------------
__global__ __launch_bounds__(256) void rmsnorm_k(
    const float* __restrict__ x, const float* __restrict__ w, u16* __restrict__ xn)
{
  long row = blockIdx.x;
  int tid = threadIdx.x;
  int l = tid & 63, wv = tid >> 6;
  f32x4 v = ((const f32x4*)(x + row * D_))[tid];
  float ss = v[0]*v[0] + v[1]*v[1] + v[2]*v[2] + v[3]*v[3];
  #pragma unroll
  for (int m = 1; m < 64; m <<= 1) ss += __shfl_xor(ss, m, 64);
  __shared__ float red[4];
  if (l == 0) red[wv] = ss;
  __syncthreads();
  float tot = red[0] + red[1] + red[2] + red[3];
  float inv = rsqrtf(tot * (1.f / (float)D_) + 1e-6f);
  f32x4 wv4 = ((const f32x4*)w)[tid];
  u16x4 o;
  o[0] = f2bf(v[0] * inv * wv4[0]);
  o[1] = f2bf(v[1] * inv * wv4[1]);
  o[2] = f2bf(v[2] * inv * wv4[2]);
  o[3] = f2bf(v[3] * inv * wv4[3]);
  ((u16x4*)(xn + row * D_))[tid] = o;
}

// ---------------- 256x256 8-phase-style pipelined bf16 NT GEMM ----------------
// BK=64, 8 waves (2x4), 2 x 64KB LDS buffers (128KB dynamic), 4 phases/K-step,
// quadrant order Q00,Q10,Q11,Q01; 8KB stage-units scheduled so each unit is
// staged >=1 barrier after its region's last read and vmcnt-covered >=1 barrier
// before its first read. vmcnt(7)@ph0, vmcnt(5)@ph3 (never 0). XOR swizzle
// byte ^= (row&7)<<4 on reads, inverse-swizzled global source on stage.
extern __shared__ f32x4 lds_dyn[];

#define MMQ(AF, BF, MO, NO) \
  __builtin_amdgcn_s_setprio(1); \
  _Pragma("unroll") \
  for (int mi = 0; mi < 4; ++mi) \
    _Pragma("unroll") \
    for (int ni = 0; ni < 2; ++ni) \
      _Pragma("unroll") \
      for (int ks = 0; ks < 2; ++ks) \
        acc[(MO)+mi][(NO)+ni] = __builtin_amdgcn_mfma_f32_16x16x32_bf16( \
            AF[mi][ks], BF[ni][ks], acc[(MO)+mi][(NO)+ni], 0, 0, 0); \
  __builtin_amdgcn_s_setprio(0);

template<int RESID, int OUTF32>
__global__ __launch_bounds__(512, 2) void gemm8p(
    const u16* __restrict__ A, const u16* __restrict__ Bm,
    u16* __restrict__ Cb, float* __restrict__ Cf, const float* __restrict__ resid,
    int M, int N, int Kd)
{
  const int tid = threadIdx.x;
  const int w = tid >> 6, l = tid & 63;
  const int lm = l & 15, lq = l >> 4;
  const int wm = w >> 2, wn = w & 3;

  unsigned gx = gridDim.x;
  unsigned bid = blockIdx.y * gx + blockIdx.x;
  unsigned nwg = gx * gridDim.y;
  unsigned cpx = nwg >> 3;
  unsigned swz = (bid & 7) * cpx + (bid >> 3);
  const long bm0 = (long)(swz / gx) * 256;
  const long bn0 = (long)(swz % gx) * 256;

  char* lds = (char*)lds_dyn;
  const int NTS = Kd >> 6;      // 16 for K=1024

  // A stage unit: 64 contiguous rows at rowBase (8KB); 1 gload/thread.
  // LDS linear dest; global k-chunk = slot ^ (row&7) (inverse swizzle).
  auto STAGE_AU = [&](int t, int rowBase){
    if (t >= NTS) return;
    char* base = lds + (t & 1) * 65536;           // A region at +0
    int c = w*64 + l;
    int row = rowBase + (c >> 3);
    int kc = (c & 7) ^ (row & 7);
    gload_lds16(A + (bm0 + row)*(long)Kd + (long)t*64 + kc*8,
                (u16*)(base + rowBase*128 + c*16));
  };
  // B stage unit: two 32-row stripes {sb..sb+31, sb+64..sb+95} (8KB).
  auto STAGE_BU = [&](int t, int sb){
    if (t >= NTS) return;
    char* base = lds + (t & 1) * 65536 + 32768;   // B region at +32KB
    int stripeBase = sb + (w >> 2) * 64;
    int ci = (w & 3)*64 + l;                      // 0..255 within stripe
    int row = stripeBase + (ci >> 3);
    int kc = (ci & 7) ^ (row & 7);
    gload_lds16(Bm + (bn0 + row)*(long)Kd + (long)t*64 + kc*8,
                (u16*)(base + stripeBase*128 + (w & 3)*1024 + l*16));
  };

  auto RD_A = [&](const char* Ab, int qm, bf16x8 afr[4][2]){
    #pragma unroll
    for (int mi = 0; mi < 4; ++mi) {
      int rr = wm*128 + qm*64 + mi*16 + lm;
      #pragma unroll
      for (int ks = 0; ks < 2; ++ks)
        afr[mi][ks] = *(const bf16x8*)(Ab + rr*128 + ((ks*64 + lq*16) ^ ((rr & 7) << 4)));
    }
  };
  auto RD_B = [&](const char* Bb, int qn, bf16x8 bfr[2][2]){
    #pragma unroll
    for (int ni = 0; ni < 2; ++ni) {
      int rr = wn*64 + qn*32 + ni*16 + lm;
      #pragma unroll
      for (int ks = 0; ks < 2; ++ks)
        bfr[ni][ks] = *(const bf16x8*)(Bb + rr*128 + ((ks*64 + lq*16) ^ ((rr & 7) << 4)));
    }
  };

  f32x4 acc[8][4];
  #pragma unroll
  for (int i = 0; i < 8; ++i)
    #pragma unroll
    for (int j = 0; j < 4; ++j) acc[i][j] = f32x4{0.f,0.f,0.f,0.f};

  bf16x8 afr0[4][2], afr1[4][2], bfr[2][2];

  // prologue: step0 all 8 units, step1 all but B1b (7 units) = 15 loads
  STAGE_AU(0, 0);   STAGE_AU(0, 128); STAGE_BU(0, 0);  STAGE_BU(0, 128);
  STAGE_AU(0, 64);  STAGE_AU(0, 192); STAGE_BU(0, 32); STAGE_BU(0, 160);
  STAGE_AU(1, 0);   STAGE_AU(1, 128); STAGE_BU(1, 0);  STAGE_BU(1, 128);
  STAGE_AU(1, 64);  STAGE_AU(1, 192); STAGE_BU(1, 32);
  asm volatile("s_waitcnt vmcnt(7)" ::: "memory");   // step0's 8 complete
  __builtin_amdgcn_s_barrier();

  for (int t = 0; t < NTS; ++t) {
    const char* Ab = lds + (t & 1) * 65536;
    const char* Bb = Ab + 32768;

    // ---- ph0: Q00 (A0 rows, B0 stripes) ----
    asm volatile("s_waitcnt vmcnt(7)" ::: "memory");   // completes B1b(t) (staged t-1 ph0)
    RD_A(Ab, 0, afr0);
    RD_B(Bb, 0, bfr);
    STAGE_BU(t + 1, 160);                              // B1b(t+1) -> other buffer
    __builtin_amdgcn_s_barrier();
    asm volatile("s_waitcnt lgkmcnt(0)" ::: "memory");
    __builtin_amdgcn_sched_barrier(0);
    MMQ(afr0, bfr, 0, 0);
    __builtin_amdgcn_s_barrier();

    // ---- ph1: Q10 (A1 rows, B0 regs) ----
    RD_A(Ab, 1, afr1);
    STAGE_AU(t + 2, 0);                                // A0a(t+2): rows 0-63 dead after ph0
    __builtin_amdgcn_s_barrier();
    asm volatile("s_waitcnt lgkmcnt(0)" ::: "memory");
    __builtin_amdgcn_sched_barrier(0);
    MMQ(afr1, bfr, 4, 0);
    __builtin_amdgcn_s_barrier();

    // ---- ph2: Q11 (A1 regs, B1 stripes) ----
    RD_B(Bb, 1, bfr);                                  // overwrite B0 regs with B1
    STAGE_AU(t + 2, 128);                              // A0b: rows 128-191 dead after ph0
    STAGE_BU(t + 2, 0);                                // B0a: dead after ph0
    STAGE_AU(t + 2, 64);                               // A1a: rows 64-127 dead after ph1
    __builtin_amdgcn_s_barrier();
    asm volatile("s_waitcnt lgkmcnt(0)" ::: "memory");
    __builtin_amdgcn_sched_barrier(0);
    MMQ(afr1, bfr, 4, 2);
    __builtin_amdgcn_s_barrier();

    // ---- ph3: Q01 (A0 regs, B1 regs) ----
    asm volatile("s_waitcnt vmcnt(5)" ::: "memory");   // completes all (t+1)-units staged at t-1
    STAGE_BU(t + 2, 128);                              // B0b: dead after ph0
    STAGE_AU(t + 2, 192);                              // A1b: rows 192-255 dead after ph1
    STAGE_BU(t + 2, 32);                               // B1a: dead after ph2
    __builtin_amdgcn_s_barrier();
    MMQ(afr0, bfr, 0, 2);
    __builtin_amdgcn_s_barrier();
  }

  // epilogue (C/D layout: col=lane&15, row=(lane>>4)*4+reg)
  #pragma unroll
  for (int mf = 0; mf < 8; ++mf) {
    #pragma unroll
    for (int r = 0; r < 4; ++r) {
      long m = bm0 + wm*128 + mf*16 + lq*4 + r;
      #pragma unroll
      for (int nf = 0; nf < 4; ++nf) {
        long n = bn0 + wn*64 + nf*16 + lm;
        float val = acc[mf][nf][r];
        if (RESID) val += resid[m * N + n];
        if (OUTF32) Cf[m * N + n] = val;
        else        Cb[m * N + n] = f2bf(val);
      }
    }
  }
}

// ---------------- fallback bf16 NT GEMM (validated, 128^2) ----------------
template<int RESID, int OUTF32>
__global__ __launch_bounds__(256) void gemm_nt(
    const u16* __restrict__ A, const u16* __restrict__ Bm,
    u16* __restrict__ Cb, float* __restrict__ Cf, const float* __restrict__ resid,
    int M, int N, int Kd)
{
  __shared__ __align__(16) u16 Als[128 * 32];
  __shared__ __align__(16) u16 Bls[128 * 32];
  const int tid = threadIdx.x;
  const int w = tid >> 6, l = tid & 63;
  const int wr = w >> 1, wc = w & 1;
  const int lm = l & 15, lq = l >> 4;

  unsigned bid = blockIdx.y * gridDim.x + blockIdx.x;
  unsigned nwg = gridDim.x * gridDim.y;
  unsigned cpx = nwg >> 3;
  unsigned swz = (bid & 7) * cpx + (bid >> 3);
  const long bm0 = (long)(swz / gridDim.x) * 128;
  const long bn0 = (long)(swz % gridDim.x) * 128;

  f32x4 zero4 = {0.f, 0.f, 0.f, 0.f};
  f32x4 acc[4][4];
  #pragma unroll
  for (int i = 0; i < 4; i++)
    #pragma unroll
    for (int j = 0; j < 4; j++) acc[i][j] = zero4;

  for (int kk = 0; kk < Kd; kk += 32) {
    __syncthreads();
    #pragma unroll
    for (int it = 0; it < 2; it++) {
      int c = tid + it * 256;
      int r = c >> 2, kb = c & 3;
      const u16* ga = A  + (bm0 + r) * Kd + kk + kb * 8;
      const u16* gb = Bm + (bn0 + r) * Kd + kk + kb * 8;
      gload_lds16(ga, Als + (it * 256 + w * 64) * 8);
      gload_lds16(gb, Bls + (it * 256 + w * 64) * 8);
    }
    __syncthreads();
    bf16x8 af[4], bfr[4];
    #pragma unroll
    for (int f = 0; f < 4; f++)
      af[f] = *(const bf16x8*)(Als + (wr * 64 + f * 16 + lm) * 32 + lq * 8);
    #pragma unroll
    for (int f = 0; f < 4; f++)
      bfr[f] = *(const bf16x8*)(Bls + (wc * 64 + f * 16 + lm) * 32 + lq * 8);
    #pragma unroll
    for (int i = 0; i < 4; i++)
      #pragma unroll
      for (int j = 0; j < 4; j++)
        acc[i][j] = __builtin_amdgcn_mfma_f32_16x16x32_bf16(af[i], bfr[j], acc[i][j], 0, 0, 0);
  }

  #pragma unroll
  for (int i = 0; i < 4; i++) {
    #pragma unroll
    for (int r = 0; r < 4; r++) {
      long m = bm0 + wr * 64 + i * 16 + lq * 4 + r;
      #pragma unroll
      for (int j = 0; j < 4; j++) {
        long n = bn0 + wc * 64 + j * 16 + lm;
        float val = acc[i][j][r];
        if (RESID) val += resid[m * N + n];
        if (OUTF32) Cf[m * N + n] = val;
        else        Cb[m * N + n] = f2bf(val);
      }
    }
  }
}

// ---------------- sigmoid for beta/g ----------------
__global__ __launch_bounds__(256) void sigmoid_bg(
    const u16* __restrict__ kv, const float* __restrict__ bb, const float* __restrict__ bg,
    float* __restrict__ bArr, float* __restrict__ gArr)
{
  int idx = blockIdx.x * 256 + threadIdx.x;   // ROWS*32 total
  int row = idx >> 5, c = idx & 31;
  int h = c & 15;
  float val = bf2f(kv[(long)row * NPAD + 2048 + c]) + ((c < 16) ? bb[h] : bg[h]);
  float s = 1.f / (1.f + expf(-val));
  long b = row >> 12, t = row & 4095;
  float* dst = (c < 16) ? bArr : gArr;
  dst[(b * H_ + h) * (long)T_ + t] = s;
}

// 64x64x64 NT matmul from LDS bf16 tiles (stride 72)
__device__ __forceinline__ void mm64(const u16* Ab, const u16* Bb,
                                     int lm, int lq, int wr, int wc, f32x4 acc[2][2])
{
  #pragma unroll
  for (int ks = 0; ks < 2; ++ks) {
    bf16x8 af[2], bfr[2];
    #pragma unroll
    for (int mi = 0; mi < 2; ++mi)
      af[mi] = *(const bf16x8*)(Ab + (wr*32 + mi*16 + lm)*72 + ks*32 + lq*8);
    #pragma unroll
    for (int ni = 0; ni < 2; ++ni)
      bfr[ni] = *(const bf16x8*)(Bb + (wc*32 + ni*16 + lm)*72 + ks*32 + lq*8);
    #pragma unroll
    for (int mi = 0; mi < 2; ++mi)
      #pragma unroll
      for (int ni = 0; ni < 2; ++ni)
        acc[mi][ni] = __builtin_amdgcn_mfma_f32_16x16x32_bf16(af[mi], bfr[ni], acc[mi][ni], 0, 0, 0);
  }
}

// ---------------- phase 1: per-chunk WY factors ----------------
__global__ __launch_bounds__(256) void chunk1(
    u16* __restrict__ kv, const float* __restrict__ bArr, const float* __restrict__ gArr,
    u16* __restrict__ p1buf, u16* __restrict__ r1buf)
{
  __shared__ __align__(16) u16 Kb[64*72];      // raw K chunk [s][k]
  __shared__ __align__(16) u16 Utb[128*72];    // V staged -> U^T
  __shared__ __align__(16) u16 LpI[64*72];
  __shared__ __align__(16) u16 Abf[64*72];     // off-diag A (diag zero) -> later Ktb
  __shared__ __align__(16) u16 Adb[4*16*24];   // bf16 diag-block A, stride 24
  __shared__ float nrm2LS[64];
  __shared__ float aLS[64], ainvLS[64], bLS[64], bapLS[64];
  __shared__ float aCsh;

  const int tid = threadIdx.x;
  const int w = tid >> 6, l = tid & 63;
  const int lm = l & 15, lq = l >> 4;
  const int wr = w >> 1, wc = w & 1;
  const int bh = blockIdx.x & 63, ch = blockIdx.x >> 6;
  const int b = bh >> 4, h = bh & 15;

  const u16* kbase = kv + ((long)b*T_ + ch*64)*NPAD + h*64;
  const u16* vbase = kbase + 1024;

  #pragma unroll
  for (int it = 0; it < 2; ++it) {
    int c = tid + it*256;
    int r = c >> 3, seg = (c & 7)*8;
    *(u16x8*)(Kb  + r*72 + seg) = *(const u16x8*)(kbase + (long)r*NPAD + seg);
    *(u16x8*)(Utb + r*72 + seg) = *(const u16x8*)(vbase + (long)r*NPAD + seg);
  }
  #pragma unroll
  for (int z = 0; z < 8; ++z) {
    int idx = tid + z*256;
    int rr = idx >> 5, wd = idx & 31;
    ((unsigned int*)(Utb + (64 + rr)*72))[wd] = 0u;
  }
  if (tid < 64) {
    float gv = gArr[(long)bh*T_ + ch*64 + tid];
    float bv = bArr[(long)bh*T_ + ch*64 + tid];
    float av = gv;
    #pragma unroll
    for (int off = 1; off < 64; off <<= 1) {
      float o = __shfl_up(av, off, 64);
      if (tid >= off) av *= o;
    }
    float ap = __shfl_up(av, 1, 64);
    if (tid == 0) ap = 1.f;
    float aC = __shfl(av, 63, 64);
    aLS[tid] = av; ainvLS[tid] = 1.f/av; bLS[tid] = bv; bapLS[tid] = bv*ap;
    if (tid == 0) aCsh = aC;
  }
  __syncthreads();   // bar1

  f32x4 gf[2][2];
  #pragma unroll
  for (int mi = 0; mi < 2; ++mi)
    #pragma unroll
    for (int ni = 0; ni < 2; ++ni) gf[mi][ni] = f32x4{0.f,0.f,0.f,0.f};
  mm64(Kb, Kb, lm, lq, wr, wc, gf);

  #pragma unroll
  for (int mi = 0; mi < 2; ++mi)
    #pragma unroll
    for (int ni = 0; ni < 2; ++ni)
      #pragma unroll
      for (int r = 0; r < 4; ++r) {
        int row = wr*32 + mi*16 + lq*4 + r, col = wc*32 + ni*16 + lm;
        if (row == col) nrm2LS[row] = gf[mi][ni][r];
      }
  __syncthreads();   // bar1.5
  if (tid < 64) {
    float nv = 1.f / fmaxf(sqrtf(nrm2LS[tid]), 1e-12f);
    aLS[tid] *= nv; ainvLS[tid] *= nv; bapLS[tid] *= nv;
  }
  __syncthreads();   // bar1.75

  float wv_[4][2][4];
  #pragma unroll
  for (int bi = 0; bi < 4; ++bi)
    #pragma unroll
    for (int ni = 0; ni < 2; ++ni) {
      int col = w*32 + ni*16 + lm;
      #pragma unroll
      for (int r = 0; r < 4; ++r) {
        int row = bi*16 + lq*4 + r;
        float sv = (col < 64) ? bf2f(Utb[row*72 + col]) : bf2f(Kb[row*72 + (col - 64)]);
        float coef = (col < 64) ? bLS[row] : bapLS[row];
        wv_[bi][ni][r] = coef * sv;
      }
    }

  #pragma unroll
  for (int mi = 0; mi < 2; ++mi)
    #pragma unroll
    for (int ni = 0; ni < 2; ++ni)
      #pragma unroll
      for (int r = 0; r < 4; ++r) {
        int row = wr*32 + mi*16 + lq*4 + r, col = wc*32 + ni*16 + lm;
        float gvl = gf[mi][ni][r];
        int rb = row >> 4, cb = col >> 4;
        Abf[row*72 + col] = f2bf((rb > cb) ? bapLS[row]*ainvLS[col]*gvl : 0.f);
        if (rb == cb)
          Adb[rb*384 + (row & 15)*24 + (col & 15)] =
              f2bf(((col & 15) < (row & 15)) ? bapLS[row]*ainvLS[col]*gvl : 0.f);
        LpI[row*72 + col] = f2bf((col < row) ? aLS[row]*ainvLS[col]*gvl
                                             : ((col == row) ? 1.f : 0.f));
      }
  __syncthreads();   // bar2

  #pragma unroll
  for (int bi = 0; bi < 4; ++bi) {
    if (bi > 0) {
      f32x4 corr[2] = { f32x4{0.f,0.f,0.f,0.f}, f32x4{0.f,0.f,0.f,0.f} };
      const int nks = (bi*16 + 31) >> 5;
      #pragma unroll
      for (int ks = 0; ks < 2; ++ks) {
        if (ks < nks) {
          bf16x8 afr = *(const bf16x8*)(Abf + (bi*16 + lm)*72 + ks*32 + lq*8);
          #pragma unroll
          for (int ni = 0; ni < 2; ++ni) {
            bf16x8 bfrv = *(const bf16x8*)(Utb + (w*32 + ni*16 + lm)*72 + ks*32 + lq*8);
            corr[ni] = __builtin_amdgcn_mfma_f32_16x16x32_bf16(afr, bfrv, corr[ni], 0, 0, 0);
          }
        }
      }
      #pragma unroll
      for (int ni = 0; ni < 2; ++ni)
        #pragma unroll
        for (int r = 0; r < 4; ++r) wv_[bi][ni][r] -= corr[ni][r];
    }
    u16x8 ad0[4], ad1[4];
    #pragma unroll
    for (int r = 0; r < 4; ++r) {
      ad0[r] = *(const u16x8*)(Adb + bi*384 + (lq*4 + r)*24);
      ad1[r] = *(const u16x8*)(Adb + bi*384 + (lq*4 + r)*24 + 8);
    }
    #pragma unroll
    for (int i = 0; i < 16; ++i) {
      int src = ((i >> 2) << 4) | lm;
      float u0 = __shfl(wv_[bi][0][i & 3], src, 64);
      float u1 = __shfl(wv_[bi][1][i & 3], src, 64);
      #pragma unroll
      for (int r = 0; r < 4; ++r) {
        float ad = bf2f((i < 8) ? ad0[r][i] : ad1[r][i - 8]);
        wv_[bi][0][r] = fmaf(-ad, u0, wv_[bi][0][r]);
        wv_[bi][1][r] = fmaf(-ad, u1, wv_[bi][1][r]);
      }
    }
    #pragma unroll
    for (int ni = 0; ni < 2; ++ni) {
      int col = w*32 + ni*16 + lm;
      #pragma unroll
      for (int r = 0; r < 4; ++r)
        Utb[col*72 + bi*16 + lq*4 + r] = f2bf(wv_[bi][ni][r]);
    }
  }
  __syncthreads();   // bar3

  const long pr_base = (((long)bh*64 + ch)*64);
  u16* qdst = kv + ((long)b*T_ + ch*64)*NPAD + h*64;
  u16* mdst = qdst + 1024;
  f32x4 acc[2][2];

  #pragma unroll
  for (int mi = 0; mi < 2; ++mi)
    #pragma unroll
    for (int ni = 0; ni < 2; ++ni) acc[mi][ni] = f32x4{0.f,0.f,0.f,0.f};
  mm64(Utb, LpI, lm, lq, wr, wc, acc);
  #pragma unroll
  for (int mi = 0; mi < 2; ++mi)
    #pragma unroll
    for (int ni = 0; ni < 2; ++ni)
      #pragma unroll
      for (int r = 0; r < 4; ++r) {
        int row = wr*32 + mi*16 + lq*4 + r, col = wc*32 + ni*16 + lm;
        p1buf[(pr_base + row)*64 + col] = f2bf(acc[mi][ni][r]);
      }

  #pragma unroll
  for (int mi = 0; mi < 2; ++mi)
    #pragma unroll
    for (int ni = 0; ni < 2; ++ni) acc[mi][ni] = f32x4{0.f,0.f,0.f,0.f};
  mm64(LpI, Utb + 64*72, lm, lq, wr, wc, acc);
  #pragma unroll
  for (int mi = 0; mi < 2; ++mi)
    #pragma unroll
    for (int ni = 0; ni < 2; ++ni)
      #pragma unroll
      for (int r = 0; r < 4; ++r) {
        int row = wr*32 + mi*16 + lq*4 + r, col = wc*32 + ni*16 + lm;
        float val = aLS[row]*bf2f(Kb[row*72 + col]) - acc[mi][ni][r];
        qdst[(long)row*NPAD + col] = f2bf(val);
      }

  {
    int s = tid & 63, kk0 = (tid >> 6) * 16;
    float coef = aCsh * ainvLS[s];
    #pragma unroll
    for (int j = 0; j < 16; ++j)
      Abf[(kk0 + j)*72 + s] = f2bf(coef * bf2f(Kb[s*72 + kk0 + j]));
  }
  __syncthreads();   // bar4

  #pragma unroll
  for (int mi = 0; mi < 2; ++mi)
    #pragma unroll
    for (int ni = 0; ni < 2; ++ni) acc[mi][ni] = f32x4{0.f,0.f,0.f,0.f};
  mm64(Utb, Abf, lm, lq, wr, wc, acc);
  #pragma unroll
  for (int mi = 0; mi < 2; ++mi)
    #pragma unroll
    for (int ni = 0; ni < 2; ++ni)
      #pragma unroll
      for (int r = 0; r < 4; ++r) {
        int row = wr*32 + mi*16 + lq*4 + r, col = wc*32 + ni*16 + lm;
        r1buf[(pr_base + row)*64 + col] = f2bf(acc[mi][ni][r]);
      }

  #pragma unroll
  for (int mi = 0; mi < 2; ++mi)
    #pragma unroll
    for (int ni = 0; ni < 2; ++ni) acc[mi][ni] = f32x4{0.f,0.f,0.f,0.f};
  mm64(Abf, Utb + 64*72, lm, lq, wr, wc, acc);
  #pragma unroll
  for (int mi = 0; mi < 2; ++mi)
    #pragma unroll
    for (int ni = 0; ni < 2; ++ni)
      #pragma unroll
      for (int r = 0; r < 4; ++r) {
        int row = wr*32 + mi*16 + lq*4 + r, col = wc*32 + ni*16 + lm;
        float val = ((row == col) ? aCsh : 0.f) - acc[mi][ni][r];
        mdst[(long)row*NPAD + col] = f2bf(val);
      }
}

// ---------------- phase 2: sequential chunk recurrence ----------------
struct PF { u16x8 qf0, qf1, mf0, mf1; u16 p1[4]; u16 r1[4]; };

__global__ __launch_bounds__(256) void chunk2(
    const u16* __restrict__ kv, const u16* __restrict__ p1buf, const u16* __restrict__ r1buf,
    u16* __restrict__ outb)
{
  __shared__ __align__(16) u16 Zb[16*72];
  __shared__ __align__(16) u16 ot[64*24];
  const int tid = threadIdx.x;
  const int wcv = tid >> 6, l = tid & 63;
  const int lm = l & 15, lq = l >> 4;
  const int bh = blockIdx.x & 63, vg = blockIdx.x >> 6;
  const int b = bh >> 4, h = bh & 15;

  for (int idx = tid; idx < 16*72/2; idx += 256) ((unsigned int*)Zb)[idx] = 0u;

  const u16* pbase = p1buf + (long)bh*64*4096;
  const u16* rbase = r1buf + (long)bh*64*4096;

  auto LOADPF = [&](int ch, PF& p){
    long rq = ((long)b*T_ + ch*64 + wcv*16 + lm)*NPAD + h*64 + lq*8;
    p.qf0 = *(const u16x8*)(kv + rq);
    p.qf1 = *(const u16x8*)(kv + rq + 32);
    p.mf0 = *(const u16x8*)(kv + rq + 1024);
    p.mf1 = *(const u16x8*)(kv + rq + 1024 + 32);
    #pragma unroll
    for (int r = 0; r < 4; ++r) {
      long pv = (long)ch*4096 + (vg*16 + lq*4 + r)*64 + wcv*16 + lm;
      p.p1[r] = pbase[pv];
      p.r1[r] = rbase[pv];
    }
  };

  PF A, Bp;
  LOADPF(0, A);
  __syncthreads();

  auto STEP = [&](int ch, PF& use, PF& pre){
    bf16x8 za0 = *(const bf16x8*)(Zb + lm*72 + lq*8);
    bf16x8 za1 = *(const bf16x8*)(Zb + lm*72 + 32 + lq*8);
    if (ch < 63) LOADPF(ch + 1, pre);
    f32x4 accO = { bf2f(use.p1[0]), bf2f(use.p1[1]), bf2f(use.p1[2]), bf2f(use.p1[3]) };
    accO = __builtin_amdgcn_mfma_f32_16x16x32_bf16(za0, as_bf(use.qf0), accO, 0, 0, 0);
    accO = __builtin_amdgcn_mfma_f32_16x16x32_bf16(za1, as_bf(use.qf1), accO, 0, 0, 0);
    f32x4 accS = { bf2f(use.r1[0]), bf2f(use.r1[1]), bf2f(use.r1[2]), bf2f(use.r1[3]) };
    accS = __builtin_amdgcn_mfma_f32_16x16x32_bf16(za0, as_bf(use.mf0), accS, 0, 0, 0);
    accS = __builtin_amdgcn_mfma_f32_16x16x32_bf16(za1, as_bf(use.mf1), accS, 0, 0, 0);
    #pragma unroll
    for (int r = 0; r < 4; ++r) ot[(wcv*16 + lm)*24 + lq*4 + r] = f2bf(accO[r]);
    __syncthreads();
    #pragma unroll
    for (int r = 0; r < 4; ++r) Zb[(lq*4 + r)*72 + wcv*16 + lm] = f2bf(accS[r]);
    {
      int i2 = tid >> 2, q4 = tid & 3;
      u16x4 ov = *(const u16x4*)(ot + i2*24 + q4*4);
      *(u16x4*)(outb + ((long)b*T_ + ch*64 + i2)*D_ + h*64 + vg*16 + q4*4) = ov;
    }
    __syncthreads();
  };

  for (int c2 = 0; c2 < 32; ++c2) {
    STEP(2*c2,     A, Bp);
    STEP(2*c2 + 1, Bp, A);
  }
}

extern "C" void kernel_launch(void* const* d_in, const int* in_sizes, int n_in,
                              void* d_out, int out_size, void* d_ws, size_t ws_size,
                              hipStream_t stream) {
  const float* x     = (const float*)d_in[0];
  const float* normw = (const float*)d_in[1];
  const float* Wk    = (const float*)d_in[2];
  const float* Wv    = (const float*)d_in[3];
  const float* Wo    = (const float*)d_in[4];
  const float* Wb    = (const float*)d_in[5];
  const float* bb    = (const float*)d_in[6];
  const float* Wg    = (const float*)d_in[7];
  const float* bg    = (const float*)d_in[8];
  float* y = (float*)d_out;

  char* ws = (char*)d_ws;
  u16* xn    = (u16*)ws;   ws += (long)ROWS * D_ * 2;      // 33.5 MB (reused as P1^T)
  u16* Wcomb = (u16*)ws;   ws += (long)NPAD * D_ * 2;      // 4.7 MB
  u16* Wob   = (u16*)ws;   ws += (long)D_ * D_ * 2;        // 2 MB
  u16* kvb   = (u16*)ws;   ws += (long)ROWS * NPAD * 2;    // 75.5 MB (k,v -> Q,M in place)
  float* bA  = (float*)ws; ws += (long)B_ * H_ * T_ * 4;
  float* gA  = (float*)ws; ws += (long)B_ * H_ * T_ * 4;
  u16* outb  = (u16*)ws;   ws += (long)ROWS * D_ * 2;
  u16* r1b   = (u16*)ws;   ws += (long)64 * 64 * 4096 * 2; // R1^T

  const int LDSB = 2 * 65536;   // 128 KB, 2-buffer 4-phase pipeline
  bool big = true;
  if (hipFuncSetAttribute(reinterpret_cast<const void*>(gemm8p<0,0>),
        hipFuncAttributeMaxDynamicSharedMemorySize, LDSB) != hipSuccess) big = false;
  if (hipFuncSetAttribute(reinterpret_cast<const void*>(gemm8p<1,1>),
        hipFuncAttributeMaxDynamicSharedMemorySize, LDSB) != hipSuccess) big = false;

  const long prep_total = (long)NPAD * D_ + (long)D_ * D_;
  prep_w<<<dim3((unsigned)(prep_total / 256)), dim3(256), 0, stream>>>(
      Wk, Wv, Wb, Wg, Wo, Wcomb, Wob);
  rmsnorm_k<<<dim3(ROWS), dim3(256), 0, stream>>>(x, normw, xn);
  if (big)
    gemm8p<0, 0><<<dim3(NPAD / 256, ROWS / 256), dim3(512), LDSB, stream>>>(
        xn, Wcomb, kvb, (float*)nullptr, (const float*)nullptr, ROWS, NPAD, D_);
  else
    gemm_nt<0, 0><<<dim3(NPAD / 128, ROWS / 128), dim3(256), 0, stream>>>(
        xn, Wcomb, kvb, (float*)nullptr, (const float*)nullptr, ROWS, NPAD, D_);
  sigmoid_bg<<<dim3(ROWS * 32 / 256), dim3(256), 0, stream>>>(kvb, bb, bg, bA, gA);
  chunk1<<<dim3(4096), dim3(256), 0, stream>>>(kvb, bA, gA, xn, r1b);
  chunk2<<<dim3(256), dim3(256), 0, stream>>>(kvb, xn, r1b, outb);
  if (big)
    gemm8p<1, 1><<<dim3(D_ / 256, ROWS / 256), dim3(512), LDSB, stream>>>(
        outb, Wob, (u16*)nullptr, y, x, ROWS, D_, D_);
  else
    gemm_nt<1, 1><<<dim3(D_ / 128, ROWS / 128), dim3(256), 0, stream>>>(
        outb, Wob, (u16*)nullptr, y, x, ROWS, D_, D_);
}